// Round 6
// baseline (190.064 us; speedup 1.0000x reference)
//
#include <hip/hip_runtime.h>

// Problem constants (fixed by the reference harness).
#define BB 64
#define SS 2048
#define DD 256
#define NQ 4          // D-quarters (fallback kernel)
#define DQ (DD / NQ)
#define NT 1024
#define NW (NT / 64)

#define FLT_BIG 3.4028234e38f

typedef float f32x4 __attribute__((ext_vector_type(4)));

// ===========================================================================
// Two-stage path: split S (not D) so every block streams CONTIGUOUS memory.
// Stage 1: block (sq, b) owns rows [sq*256, sq*256+256) of doc b — a
// contiguous 256 KiB slab. 512 threads: lane = full-row float4 column
// (64 lanes x 16 B = one whole 1 KiB row per wave-load), wid = tid>>6 picks
// the row within each 8-row step. 2 blocks/CU so prologue/epilogue tails of
// one block overlap the other's streaming. Partial stats (unnormalized) go
// to workspace; stage 2 folds 8 partials/doc and writes the output.
// ===========================================================================
#define S1_ROWS 256
#define S1_NT 512
#define S1_NW 8
#define PART_STRIDE (5 * 256)  // floats per (b,sq) partial record
#define WSUM_OFF (BB * 8 * PART_STRIDE)

__global__ __launch_bounds__(S1_NT, 4) void stage1(
    const int* __restrict__ chunk, const float* __restrict__ enc,
    const float* __restrict__ idf, float* __restrict__ part) {
  const int sq = blockIdx.x;  // 0..7 s-slice
  const int b = blockIdx.y;
  const int tid = threadIdx.x;
  const int lane = tid & 63;  // float4 column: cols [lane*4, lane*4+4)
  const int wid = tid >> 6;   // 0..7 row offset

  __shared__ float sw[S1_ROWS];       // this slab's idf weights
  __shared__ float warr[4];           // per-wave wsum partials (waves 0-3)
  __shared__ float red[S1_NW][64][21];  // 43 KB cross-wave combine (pad 21)

  const int s0 = sq * S1_ROWS;
  const float* base = enc + ((size_t)b * SS + s0) * DD + lane * 4;

  // Token ids first (oldest in vmcnt queue) so the idf gather's wait does
  // not drain the enc prefetch issued behind it.
  int c0 = 0;
  if (tid < S1_ROWS) c0 = chunk[b * SS + s0 + tid];

  f32x4 bufA[8], bufB[8];

#define LOADG(buf, g)                                                       \
  _Pragma("unroll") for (int k = 0; k < 8; ++k) {                           \
    buf[k] = __builtin_nontemporal_load(                                    \
        (const f32x4*)(base + (size_t)(wid + 8 * (8 * (g) + k)) * DD));     \
  }

  // Prefetch group 0 before the weight-staging barrier.
  LOADG(bufA, 0)

  if (tid < S1_ROWS) {
    float w = idf[c0];
    sw[tid] = w;
    float wp = w;
#pragma unroll
    for (int off = 32; off > 0; off >>= 1) wp += __shfl_down(wp, off, 64);
    if (lane == 0) warr[wid] = wp;
  }
  __syncthreads();

  float swe[4] = {0.f, 0.f, 0.f, 0.f};
  float se[4] = {0.f, 0.f, 0.f, 0.f};
  float se2[4] = {0.f, 0.f, 0.f, 0.f};
  float mx[4], mn[4];
#pragma unroll
  for (int k = 0; k < 4; k++) {
    mx[k] = -FLT_BIG;
    mn[k] = FLT_BIG;
  }

#define PROCG(buf, g)                                                       \
  _Pragma("unroll") for (int k = 0; k < 8; ++k) {                           \
    const int r = wid + 8 * (8 * (g) + k);                                  \
    const float w = sw[r]; /* wave-uniform: LDS broadcast */                \
    _Pragma("unroll") for (int j = 0; j < 4; ++j) {                         \
      const float e = buf[k][j];                                            \
      swe[j] = fmaf(w, e, swe[j]);                                          \
      se[j] += e;                                                           \
      se2[j] = fmaf(e, e, se2[j]);                                          \
      mx[j] = fmaxf(mx[j], e);                                              \
      mn[j] = fminf(mn[j], e);                                              \
    }                                                                       \
  }

  // 2-deep register pipeline, static buffer alternation.
  LOADG(bufB, 1)
  PROCG(bufA, 0)
  LOADG(bufA, 2)
  PROCG(bufB, 1)
  LOADG(bufB, 3)
  PROCG(bufA, 2)
  PROCG(bufB, 3)

#undef LOADG
#undef PROCG

  // Cross-wave combine: every lane owns distinct columns, so the only
  // reduction axis is the 8 wid groups -> LDS.
  {
    float* r = red[wid][lane];
#pragma unroll
    for (int j = 0; j < 4; j++) {
      r[j] = swe[j];
      r[4 + j] = se[j];
      r[8 + j] = se2[j];
      r[12 + j] = mx[j];
      r[16 + j] = mn[j];
    }
  }
  __syncthreads();

  if (tid < 256) {
    const int d4 = tid >> 2, comp = tid & 3;
    float cswe = 0.f, cse = 0.f, cse2 = 0.f;
    float cmx = -FLT_BIG, cmn = FLT_BIG;
#pragma unroll
    for (int wv = 0; wv < S1_NW; wv++) {
      const float* r = red[wv][d4];
      cswe += r[comp];
      cse += r[4 + comp];
      cse2 += r[8 + comp];
      cmx = fmaxf(cmx, r[12 + comp]);
      cmn = fminf(cmn, r[16 + comp]);
    }
    float* p = part + (size_t)(b * 8 + sq) * PART_STRIDE;
    p[tid] = cswe;
    p[256 + tid] = cse;
    p[512 + tid] = cse2;
    p[768 + tid] = cmx;
    p[1024 + tid] = cmn;
    if (tid == 0)
      part[WSUM_OFF + b * 8 + sq] = warr[0] + warr[1] + warr[2] + warr[3];
  }
}

__global__ __launch_bounds__(256) void stage2(const float* __restrict__ part,
                                              float* __restrict__ out) {
  const int b = blockIdx.x;
  const int d = threadIdx.x;  // 0..255
  const float* pb = part + (size_t)b * 8 * PART_STRIDE;
  const float* ws = part + WSUM_OFF + b * 8;
  float swe = 0.f, se = 0.f, se2 = 0.f, wtot = 0.f;
  float mx = -FLT_BIG, mn = FLT_BIG;
#pragma unroll
  for (int sq = 0; sq < 8; sq++) {
    const float* p = pb + sq * PART_STRIDE;
    swe += p[d];
    se += p[256 + d];
    se2 += p[512 + d];
    mx = fmaxf(mx, p[768 + d]);
    mn = fminf(mn, p[1024 + d]);
    wtot += ws[sq];
  }
  float mu = se / (float)SS;
  float stdv =
      sqrtf(fmaxf((se2 - (float)SS * mu * mu) / (float)(SS - 1), 0.f));
  size_t ob = (size_t)b * 4 * DD;
  out[ob + d] = swe / wtot;
  out[ob + DD + d] = mx;
  out[ob + 2 * DD + d] = mn;
  out[ob + 3 * DD + d] = stdv;
}

// ===========================================================================
// Fallback (R1's verified kernel): one block per (doc, D-quarter), all stats
// finished in-block. Used only if the workspace is too small for partials.
// ===========================================================================
__global__ __launch_bounds__(NT) void fused_kernel(
    const int* __restrict__ chunk, const float* __restrict__ enc,
    const float* __restrict__ idf, float* __restrict__ out) {
  const int dq = blockIdx.x;
  const int b = blockIdx.y;
  const int tid = threadIdx.x;
  const int lane = tid & 63;
  const int wid = tid >> 6;
  const int d4 = tid & 15;
  const int srow = tid >> 4;

  __shared__ float sw[SS];
  __shared__ float warr[NW];
  __shared__ float red[NW][16][20];

  const int c0 = chunk[b * SS + tid];
  const int c1 = chunk[b * SS + NT + tid];

  const float* base = enc + ((size_t)b * SS) * DD + dq * DQ + d4 * 4;

  f32x4 bufA[8], bufB[8];

#define LOADG(buf, g)                                                       \
  _Pragma("unroll") for (int k = 0; k < 8; ++k) {                           \
    buf[k] = __builtin_nontemporal_load(                                    \
        (const f32x4*)(base + (size_t)(srow + 64 * (8 * (g) + k)) * DD));   \
  }

  LOADG(bufA, 0)

  float w0 = idf[c0];
  float w1 = idf[c1];
  sw[tid] = w0;
  sw[NT + tid] = w1;
  float wp = w0 + w1;
#pragma unroll
  for (int off = 32; off > 0; off >>= 1) wp += __shfl_down(wp, off, 64);
  if (lane == 0) warr[wid] = wp;
  __syncthreads();

  float swe[4] = {0.f, 0.f, 0.f, 0.f};
  float se[4] = {0.f, 0.f, 0.f, 0.f};
  float se2[4] = {0.f, 0.f, 0.f, 0.f};
  float mx[4], mn[4];
#pragma unroll
  for (int k = 0; k < 4; k++) {
    mx[k] = -FLT_BIG;
    mn[k] = FLT_BIG;
  }

#define PROCG(buf, g)                                                       \
  _Pragma("unroll") for (int k = 0; k < 8; ++k) {                           \
    const int s = srow + 64 * (8 * (g) + k);                                \
    const float w = sw[s];                                                  \
    _Pragma("unroll") for (int j = 0; j < 4; ++j) {                         \
      const float e = buf[k][j];                                            \
      swe[j] = fmaf(w, e, swe[j]);                                          \
      se[j] += e;                                                           \
      se2[j] = fmaf(e, e, se2[j]);                                          \
      mx[j] = fmaxf(mx[j], e);                                              \
      mn[j] = fminf(mn[j], e);                                              \
    }                                                                       \
  }

  LOADG(bufB, 1)
  PROCG(bufA, 0)
  LOADG(bufA, 2)
  PROCG(bufB, 1)
  LOADG(bufB, 3)
  PROCG(bufA, 2)
  PROCG(bufB, 3)

#undef LOADG
#undef PROCG

#pragma unroll
  for (int j = 0; j < 4; j++) {
    swe[j] += __shfl_xor(swe[j], 32, 64);
    swe[j] += __shfl_xor(swe[j], 16, 64);
    se[j] += __shfl_xor(se[j], 32, 64);
    se[j] += __shfl_xor(se[j], 16, 64);
    se2[j] += __shfl_xor(se2[j], 32, 64);
    se2[j] += __shfl_xor(se2[j], 16, 64);
    mx[j] = fmaxf(mx[j], __shfl_xor(mx[j], 32, 64));
    mx[j] = fmaxf(mx[j], __shfl_xor(mx[j], 16, 64));
    mn[j] = fminf(mn[j], __shfl_xor(mn[j], 32, 64));
    mn[j] = fminf(mn[j], __shfl_xor(mn[j], 16, 64));
  }
  if (lane < 16) {
    float* r = red[wid][lane];
#pragma unroll
    for (int j = 0; j < 4; j++) {
      r[j] = swe[j];
      r[4 + j] = se[j];
      r[8 + j] = se2[j];
      r[12 + j] = mx[j];
      r[16 + j] = mn[j];
    }
  }
  __syncthreads();

  if (tid < DQ) {
    int f4 = tid >> 2, comp = tid & 3;
    float cswe = 0.f, cse = 0.f, cse2 = 0.f, wtot = 0.f;
    float cmx = -FLT_BIG, cmn = FLT_BIG;
#pragma unroll
    for (int wv = 0; wv < NW; wv++) {
      const float* r = red[wv][f4];
      cswe += r[comp];
      cse += r[4 + comp];
      cse2 += r[8 + comp];
      cmx = fmaxf(cmx, r[12 + comp]);
      cmn = fminf(cmn, r[16 + comp]);
      wtot += warr[wv];
    }
    float mu = cse / (float)SS;
    float stdv =
        sqrtf(fmaxf((cse2 - (float)SS * mu * mu) / (float)(SS - 1), 0.f));
    int d = dq * DQ + tid;
    size_t ob = (size_t)b * 4 * DD;
    out[ob + d] = cswe / wtot;
    out[ob + DD + d] = cmx;
    out[ob + 2 * DD + d] = cmn;
    out[ob + 3 * DD + d] = stdv;
  }
}

extern "C" void kernel_launch(void* const* d_in, const int* in_sizes, int n_in,
                              void* d_out, int out_size, void* d_ws,
                              size_t ws_size, hipStream_t stream) {
  const int* chunk = (const int*)d_in[0];
  const float* enc = (const float*)d_in[1];
  const float* idf = (const float*)d_in[2];
  float* out = (float*)d_out;

  const size_t need = (size_t)(WSUM_OFF + BB * 8) * sizeof(float);
  if (ws_size >= need && d_ws != nullptr) {
    float* part = (float*)d_ws;
    stage1<<<dim3(8, BB), S1_NT, 0, stream>>>(chunk, enc, idf, part);
    stage2<<<dim3(BB), 256, 0, stream>>>(part, out);
  } else {
    fused_kernel<<<dim3(NQ, BB), NT, 0, stream>>>(chunk, enc, idf, out);
  }
}

// Round 7
// 185.295 us; speedup vs baseline: 1.0257x; 1.0257x over previous
//
#include <hip/hip_runtime.h>

// Problem constants (fixed by the reference harness).
#define BB 64
#define SS 2048
#define DD 256
#define NQ 4          // D-quarters; one block per (doc, quarter)
#define DQ (DD / NQ)  // 64 columns per block
#define NT 1024       // threads per block (16 waves)
#define NW (NT / 64)

#define FLT_BIG 3.4028234e38f

// Native vector type so __builtin_nontemporal_load accepts it.
typedef float f32x4 __attribute__((ext_vector_type(4)));

// ---------------------------------------------------------------------------
// R1-verified best (185.9 us graded). One block = (quarter dq, doc b).
// 1024 threads: d4 = tid&15 picks a float4 column within the quarter,
// srow = tid>>4 in [0,64) staggers rows; thread covers s = srow + 64k
// (32 rows) as four groups of 8 in an explicit 2-deep register pipeline
// (bufA/bufB, static indexing so buffers stay in VGPRs). Group 0's loads
// issue BEFORE the weight-staging barrier so the cold idf gather + shuffle
// reduce + __syncthreads overlap the first 8 row loads. enc is strictly
// streaming -> nontemporal loads. All five stats finish inside the block.
//
// Measured (R6): an S-split two-stage variant with fully contiguous slabs
// and 2 blocks/CU ran 4 us SLOWER (stage-2 fold overhead, zero read-rate
// gain) -> the ~4.6 TB/s read rate is the read-path ceiling, not an access
// pattern artifact. Keep this structure.
// ---------------------------------------------------------------------------
__global__ __launch_bounds__(NT) void fused_kernel(
    const int* __restrict__ chunk, const float* __restrict__ enc,
    const float* __restrict__ idf, float* __restrict__ out) {
  const int dq = blockIdx.x;
  const int b = blockIdx.y;
  const int tid = threadIdx.x;
  const int lane = tid & 63;
  const int wid = tid >> 6;
  const int d4 = tid & 15;   // float4 column within quarter
  const int srow = tid >> 4; // 0..63

  __shared__ float sw[SS];          // 8 KiB: the doc's idf weights
  __shared__ float warr[NW];        // per-wave wsum partials
  __shared__ float red[NW][16][20]; // 20 KiB: cross-wave stat combine

  // Token-id loads first: oldest in the vmcnt queue, so the dependent idf
  // gather can wait on them without draining the enc prefetch behind them.
  const int c0 = chunk[b * SS + tid];
  const int c1 = chunk[b * SS + NT + tid];

  const float* base = enc + ((size_t)b * SS) * DD + dq * DQ + d4 * 4;

  f32x4 bufA[8], bufB[8];

#define LOADG(buf, g)                                                        \
  _Pragma("unroll") for (int k = 0; k < 8; ++k) {                            \
    buf[k] = __builtin_nontemporal_load(                                     \
        (const f32x4*)(base + (size_t)(srow + 64 * (8 * (g) + k)) * DD));    \
  }

  // Prefetch group 0 before the staging barrier.
  LOADG(bufA, 0)

  // Stage the doc's 2048 idf weights (2 gathers/thread); fold the local
  // wsum reduction into the same pass via a wave shuffle reduce.
  float w0 = idf[c0];
  float w1 = idf[c1];
  sw[tid] = w0;
  sw[NT + tid] = w1;
  float wp = w0 + w1;
#pragma unroll
  for (int off = 32; off > 0; off >>= 1) wp += __shfl_down(wp, off, 64);
  if (lane == 0) warr[wid] = wp;
  __syncthreads();

  float swe[4] = {0.f, 0.f, 0.f, 0.f};
  float se[4] = {0.f, 0.f, 0.f, 0.f};
  float se2[4] = {0.f, 0.f, 0.f, 0.f};
  float mx[4], mn[4];
#pragma unroll
  for (int k = 0; k < 4; k++) {
    mx[k] = -FLT_BIG;
    mn[k] = FLT_BIG;
  }

#define PROCG(buf, g)                                                        \
  _Pragma("unroll") for (int k = 0; k < 8; ++k) {                            \
    const int s = srow + 64 * (8 * (g) + k);                                 \
    const float w = sw[s]; /* 4 distinct consecutive addrs: conflict-free */ \
    _Pragma("unroll") for (int j = 0; j < 4; ++j) {                          \
      const float e = buf[k][j];                                             \
      swe[j] = fmaf(w, e, swe[j]);                                           \
      se[j] += e;                                                            \
      se2[j] = fmaf(e, e, se2[j]);                                           \
      mx[j] = fmaxf(mx[j], e);                                               \
      mn[j] = fminf(mn[j], e);                                               \
    }                                                                        \
  }

  // 2-deep software pipeline: next group's 8 loads are in flight while the
  // current group is consumed (static buffer alternation, no runtime index).
  LOADG(bufB, 1)
  PROCG(bufA, 0)
  LOADG(bufA, 2)
  PROCG(bufB, 1)
  LOADG(bufB, 3)
  PROCG(bufA, 2)
  PROCG(bufB, 3)

#undef LOADG
#undef PROCG

  // Combine the 4 srow-groups within each wave (lanes l, l^16, l^32, l^48
  // share the same d4). Butterfly over xor 32, 16.
#pragma unroll
  for (int j = 0; j < 4; j++) {
    swe[j] += __shfl_xor(swe[j], 32, 64);
    swe[j] += __shfl_xor(swe[j], 16, 64);
    se[j] += __shfl_xor(se[j], 32, 64);
    se[j] += __shfl_xor(se[j], 16, 64);
    se2[j] += __shfl_xor(se2[j], 32, 64);
    se2[j] += __shfl_xor(se2[j], 16, 64);
    mx[j] = fmaxf(mx[j], __shfl_xor(mx[j], 32, 64));
    mx[j] = fmaxf(mx[j], __shfl_xor(mx[j], 16, 64));
    mn[j] = fminf(mn[j], __shfl_xor(mn[j], 32, 64));
    mn[j] = fminf(mn[j], __shfl_xor(mn[j], 16, 64));
  }
  if (lane < 16) {
    float* r = red[wid][lane];
#pragma unroll
    for (int j = 0; j < 4; j++) {
      r[j] = swe[j];
      r[4 + j] = se[j];
      r[8 + j] = se2[j];
      r[12 + j] = mx[j];
      r[16 + j] = mn[j];
    }
  }
  __syncthreads();

  // 64 threads finish the quarter: column c -> (float4 f4, component comp).
  if (tid < DQ) {
    int f4 = tid >> 2, comp = tid & 3;
    float cswe = 0.f, cse = 0.f, cse2 = 0.f, wtot = 0.f;
    float cmx = -FLT_BIG, cmn = FLT_BIG;
#pragma unroll
    for (int wv = 0; wv < NW; wv++) {
      const float* r = red[wv][f4];
      cswe += r[comp];
      cse += r[4 + comp];
      cse2 += r[8 + comp];
      cmx = fmaxf(cmx, r[12 + comp]);
      cmn = fminf(cmn, r[16 + comp]);
      wtot += warr[wv];
    }
    float mu = cse / (float)SS;
    float stdv =
        sqrtf(fmaxf((cse2 - (float)SS * mu * mu) / (float)(SS - 1), 0.f));
    int d = dq * DQ + tid;
    size_t ob = (size_t)b * 4 * DD;
    out[ob + d] = cswe / wtot;
    out[ob + DD + d] = cmx;
    out[ob + 2 * DD + d] = cmn;
    out[ob + 3 * DD + d] = stdv;
  }
}

extern "C" void kernel_launch(void* const* d_in, const int* in_sizes, int n_in,
                              void* d_out, int out_size, void* d_ws,
                              size_t ws_size, hipStream_t stream) {
  const int* chunk = (const int*)d_in[0];
  const float* enc = (const float*)d_in[1];
  const float* idf = (const float*)d_in[2];
  float* out = (float*)d_out;

  fused_kernel<<<dim3(NQ, BB), NT, 0, stream>>>(chunk, enc, idf, out);
}